// Round 3
// baseline (222.603 us; speedup 1.0000x reference)
//
#include <hip/hip_runtime.h>
#include <stdint.h>

// ---------------- problem constants ----------------
#define HW_      102400          // 320*320
#define C_       256
#define N_       1024
#define P_       2               // pairs
#define CHUNKS_  64              // HW chunks per (pair, n-block)
#define CHUNK_PX 1600            // 5 rows of 320 -> chunks row-aligned
#define ITERS_   25              // 25 * 64 px = 1600 px per chunk
#define NB_      4               // n-blocks of 256 keypoints
#define K2_      144.269504088896340f   // 100 / ln(2)
#define MOFF_    (-72.134752044448170f) // -K2_ * 0.5  (fixed softmax max = 0.5 in cosine space)

typedef __attribute__((ext_vector_type(8))) short bf16x8;
typedef __attribute__((ext_vector_type(4))) float f32x4;

// ws layout (bytes):
//   tgt bf16: [0, 1048576)       2*1024*256 bf16, [p][n][c]
//   partials: [1048576, +4MB)    2*64*2*1024 float4 (S,U,V,-)
#define WS_TGT_OFF  0
#define WS_PAR_OFF  1048576

__device__ __forceinline__ uint32_t packbf(float a, float b) {
  uint32_t r;
  asm("v_cvt_pk_bf16_f32 %0, %1, %2" : "=v"(r) : "v"(a), "v"(b));
  return r;
}
__device__ __forceinline__ float fexp2(float x) {
  return __builtin_amdgcn_exp2f(x);
}

// ---------------- kernel 1: normalize tgt keypoint descs -> bf16 [p][n][c]; copy weights ----------------
__global__ __launch_bounds__(256)
void k_pre(const float* __restrict__ kdesc, const float* __restrict__ kscores,
           uint16_t* __restrict__ tgt, float* __restrict__ out) {
  const int t = blockIdx.x * 256 + threadIdx.x;   // 0..2047
  const int p = t >> 10, n = t & 1023;
  const float* src = kdesc + (size_t)(p * 2 + 1) * C_ * N_ + n;   // tgt ids 1,3
  float s = 0.f;
  #pragma unroll 16
  for (int c = 0; c < C_; ++c) { const float v = src[c * N_]; s = fmaf(v, v, s); }
  const float inv = 1.f / fmaxf(sqrtf(s), 1e-12f);
  uint32_t* dst = (uint32_t*)(tgt + (size_t)t * C_);
  #pragma unroll 4
  for (int c8 = 0; c8 < C_; c8 += 8) {
    uint4 wv;
    wv.x = packbf(src[(c8 + 0) * N_] * inv, src[(c8 + 1) * N_] * inv);
    wv.y = packbf(src[(c8 + 2) * N_] * inv, src[(c8 + 3) * N_] * inv);
    wv.z = packbf(src[(c8 + 4) * N_] * inv, src[(c8 + 5) * N_] * inv);
    wv.w = packbf(src[(c8 + 6) * N_] * inv, src[(c8 + 7) * N_] * inv);
    *(uint4*)&dst[c8 / 2] = wv;
  }
  out[4096 + t] = kscores[(p * 2 + 1) * N_ + n];   // match_weights
}

// ---------------- kernel 2: fused norm + QK^T + fixed-max softmax + soft-argmax ----------------
// Stages RAW src as bf16; per-pixel inv-norm computed in-block during staging and applied
// as a scale inside the exp. The 4 blocks sharing a (p,chunk) tile are mapped to the SAME
// XCD (bids differ by 8 under round-robin) so readers 2-4 hit L2 -> dense read from HBM once.
__global__ __launch_bounds__(512, 2)
void k_main(const float* __restrict__ dense, const uint16_t* __restrict__ tgt,
            float4* __restrict__ partials) {
  __shared__ uint32_t lds[2 * 64 * 128];   // 2 bufs x (64 px x 256 bf16), XOR-swizzled
  __shared__ float4 part4[8][16];          // per-wave sumsq partials, [wave][px/4]
  __shared__ float4 invt4[2][16];          // per-tile inv-norm, [slot][px/4]

  // ---- XCD co-locating decode: same (p,chunk) -> bids {x+32k, +8, +16, +24} ----
  const int bid   = blockIdx.x;            // 0..511
  const int xcd   = bid & 7;
  const int rr    = bid >> 3;              // 0..63
  const int grp   = xcd + 8 * (rr >> 2);   // 0..127 = (p,chunk)
  const int nb    = rr & 3;
  const int p     = grp >> 6;
  const int chunk = grp & 63;

  const int t    = threadIdx.x;
  const int lane = t & 63;
  const int w    = t >> 6;
  const int l15  = lane & 15;
  const int g4   = lane >> 4;
  const int h    = w & 1;    // m-half: 32 px
  const int q    = w >> 1;   // n-quarter: 64 keypoints

  const float* plane = dense + (size_t)(p * 2) * C_ * HW_;   // src ids 0,2

  // ---- B fragments (tgt, [n][c] bf16): lane n = l15, k-slice c = k*32 + g4*8 .. +7 ----
  bf16x8 Bf[4][8];
  const int nbase = nb * 256 + q * 64;
  #pragma unroll
  for (int j = 0; j < 4; ++j) {
    const uint16_t* tp = tgt + (size_t)(p * N_ + nbase + j * 16 + l15) * C_ + g4 * 8;
    #pragma unroll
    for (int k = 0; k < 8; ++k) Bf[j][k] = *(const bf16x8*)(tp + k * 32);
  }

  float stS[4], stU[4], stV[4];
  #pragma unroll
  for (int j = 0; j < 4; ++j) { stS[j] = 0.f; stU[j] = 0.f; stV[j] = 0.f; }

  // staging: thread t loads 8 channel rows (c8..c8+7) x 4 px (mi..mi+3), raw f32
  const int mi   = (t & 15) * 4;
  const int c8   = (t >> 4) * 8;
  const int wcol = (t >> 4) * 4;           // dword col within LDS row
  const int px0  = chunk * CHUNK_PX;

  const int row0 = h * 32 + l15;           // A-frag row (subtile 1 = +16)
  const int swr  = (row0 & 7) << 2;        // read swizzle
  const int lr0  = h * 32 + g4 * 4;        // this lane's acc row base (s=0)

  uint32_t* bufR = lds;
  uint32_t* bufW = lds + 64 * 128;

  float fva[8][4];

  // ---- prologue: load tile 0, pack raw bf16 -> bufR, sumsq -> invt[0] ----
  {
    const int px = px0 + mi;
    #pragma unroll
    for (int j = 0; j < 8; ++j) {
      float4 v = *(const float4*)(plane + (size_t)(c8 + j) * HW_ + px);
      fva[j][0] = v.x; fva[j][1] = v.y; fva[j][2] = v.z; fva[j][3] = v.w;
    }
    float ps[4];
    #pragma unroll
    for (int i = 0; i < 4; ++i) {
      const int row = mi + i;
      uint4 wv;
      wv.x = packbf(fva[0][i], fva[1][i]);
      wv.y = packbf(fva[2][i], fva[3][i]);
      wv.z = packbf(fva[4][i], fva[5][i]);
      wv.w = packbf(fva[6][i], fva[7][i]);
      *(uint4*)&bufR[row * 128 + (wcol ^ ((row & 7) << 2))] = wv;
      float s = 0.f;
      #pragma unroll
      for (int j = 0; j < 8; ++j) s = fmaf(fva[j][i], fva[j][i], s);
      ps[i] = s;
    }
    #pragma unroll
    for (int i = 0; i < 4; ++i) {
      ps[i] += __shfl_xor(ps[i], 16, 64);
      ps[i] += __shfl_xor(ps[i], 32, 64);
    }
    if (g4 == 0) part4[w][l15] = make_float4(ps[0], ps[1], ps[2], ps[3]);
  }
  __syncthreads();
  if (w == 0) {
    float s = 0.f;
    #pragma unroll
    for (int j = 0; j < 8; ++j) s += ((const float*)part4)[j * 64 + lane];
    ((float*)invt4)[lane] = 1.f / fmaxf(sqrtf(s), 1e-12f);
  }
  __syncthreads();

  for (int iter = 0; iter < ITERS_; ++iter) {
    const bool more = (iter + 1 < ITERS_);

    // ---- issue next tile's global loads (latency hides under MFMA+softmax) ----
    if (more) {
      const int px = px0 + (iter + 1) * 64 + mi;
      #pragma unroll
      for (int j = 0; j < 8; ++j) {
        float4 v = *(const float4*)(plane + (size_t)(c8 + j) * HW_ + px);
        fva[j][0] = v.x; fva[j][1] = v.y; fva[j][2] = v.z; fva[j][3] = v.w;
      }
    }

    // ---- MFMA from bufR: acc[j][s] = 16px x 16n (raw dots) ----
    f32x4 acc[4][2];
    #pragma unroll
    for (int j = 0; j < 4; ++j) {
      acc[j][0] = (f32x4){0.f, 0.f, 0.f, 0.f};
      acc[j][1] = (f32x4){0.f, 0.f, 0.f, 0.f};
    }
    #pragma unroll
    for (int k = 0; k < 8; ++k) {
      const int col = (k * 16 + g4 * 4) ^ swr;
      bf16x8 a0 = *(const bf16x8*)&bufR[row0 * 128 + col];
      bf16x8 a1 = *(const bf16x8*)&bufR[(row0 + 16) * 128 + col];
      #pragma unroll
      for (int j = 0; j < 4; ++j) {
        acc[j][0] = __builtin_amdgcn_mfma_f32_16x16x32_bf16(a0, Bf[j][k], acc[j][0], 0, 0, 0);
        acc[j][1] = __builtin_amdgcn_mfma_f32_16x16x32_bf16(a1, Bf[j][k], acc[j][1], 0, 0, 0);
      }
    }

    // ---- per-pixel inv-norm scale + fixed-max softmax + soft-argmax ----
    const int slot = iter & 1;
    float kv[8];
    {
      float4 iv0 = invt4[slot][lr0 >> 2];          // rows lr0..lr0+3   (s=0)
      float4 iv1 = invt4[slot][(lr0 >> 2) + 4];    // rows lr0+16..+19  (s=1)
      kv[0] = K2_ * iv0.x; kv[1] = K2_ * iv0.y; kv[2] = K2_ * iv0.z; kv[3] = K2_ * iv0.w;
      kv[4] = K2_ * iv1.x; kv[5] = K2_ * iv1.y; kv[6] = K2_ * iv1.z; kv[7] = K2_ * iv1.w;
    }
    const int rb = iter * 64 + lr0;
    #pragma unroll
    for (int s = 0; s < 2; ++s) {
      #pragma unroll
      for (int e = 0; e < 4; ++e) {
        const int r  = rb + s * 16 + e;            // < 1600
        const int vl = (r * 6554) >> 21;           // == r / 320
        const float vf = (float)(chunk * 5 + vl);
        const float uf = (float)(r - vl * 320);
        const float kve = kv[s * 4 + e];
        #pragma unroll
        for (int j = 0; j < 4; ++j) {
          const float ev = fexp2(fmaf(kve, acc[j][s][e], MOFF_));
          stS[j] += ev;
          stU[j] = fmaf(ev, uf, stU[j]);
          stV[j] = fmaf(ev, vf, stV[j]);
        }
      }
    }

    // ---- pack + write next tile into bufW; sumsq partials ----
    if (more) {
      float ps[4];
      #pragma unroll
      for (int i = 0; i < 4; ++i) {
        const int row = mi + i;
        uint4 wv;
        wv.x = packbf(fva[0][i], fva[1][i]);
        wv.y = packbf(fva[2][i], fva[3][i]);
        wv.z = packbf(fva[4][i], fva[5][i]);
        wv.w = packbf(fva[6][i], fva[7][i]);
        *(uint4*)&bufW[row * 128 + (wcol ^ ((row & 7) << 2))] = wv;
        float s = 0.f;
        #pragma unroll
        for (int j = 0; j < 8; ++j) s = fmaf(fva[j][i], fva[j][i], s);
        ps[i] = s;
      }
      #pragma unroll
      for (int i = 0; i < 4; ++i) {
        ps[i] += __shfl_xor(ps[i], 16, 64);
        ps[i] += __shfl_xor(ps[i], 32, 64);
      }
      if (g4 == 0) part4[w][l15] = make_float4(ps[0], ps[1], ps[2], ps[3]);
    }
    __syncthreads();                               // publish bufW + part
    if (more && w == 0) {
      float s = 0.f;
      #pragma unroll
      for (int j = 0; j < 8; ++j) s += ((const float*)part4)[j * 64 + lane];
      ((float*)invt4)[((iter + 1) & 1) * 64 + lane] = 1.f / fmaxf(sqrtf(s), 1e-12f);
    }
    __syncthreads();                               // publish invt
    uint32_t* tmp = bufR; bufR = bufW; bufW = tmp;
  }

  // ---- merge the 4 lane-groups (disjoint px subsets, same n) ----
  #pragma unroll
  for (int j = 0; j < 4; ++j) {
    float S = stS[j], U = stU[j], V = stV[j];
    S += __shfl_xor(S, 16, 64); U += __shfl_xor(U, 16, 64); V += __shfl_xor(V, 16, 64);
    S += __shfl_xor(S, 32, 64); U += __shfl_xor(U, 32, 64); V += __shfl_xor(V, 32, 64);
    if (lane < 16) {
      const int n = nbase + j * 16 + l15;
      partials[((size_t)(p * CHUNKS_ + chunk) * 2 + h) * N_ + n] = make_float4(S, U, V, 0.f);
    }
  }
}

// ---------------- kernel 3: sum 128 partials per (p, n) -> coords; ids ----------------
__global__ void k_final(const float4* __restrict__ partials, float* __restrict__ out) {
  const int t = blockIdx.x * blockDim.x + threadIdx.x;   // 0..2047
  const int p = t >> 10, n = t & 1023;
  float S = 0.f, U = 0.f, V = 0.f;
  #pragma unroll 4
  for (int s = 0; s < 2 * CHUNKS_; ++s) {
    const float4 v = partials[((size_t)p * 2 * CHUNKS_ + s) * N_ + n];
    S += v.x; U += v.y; V += v.z;
  }
  out[(size_t)(p * N_ + n) * 2 + 0] = U / S;
  out[(size_t)(p * N_ + n) * 2 + 1] = V / S;
  if (t < 4) {
    const float ids[4] = {1.f, 3.f, 0.f, 2.f};  // tgt_ids then src_ids
    out[6144 + t] = ids[t];
  }
}

// ---------------- host launch ----------------
extern "C" void kernel_launch(void* const* d_in, const int* in_sizes, int n_in,
                              void* d_out, int out_size, void* d_ws, size_t ws_size,
                              hipStream_t stream) {
  const float* kscores = (const float*)d_in[0];   // (4,1,1024)
  const float* kdesc   = (const float*)d_in[1];   // (4,256,1024)
  const float* dense   = (const float*)d_in[2];   // (4,256,320,320)
  float* out = (float*)d_out;

  char* ws = (char*)d_ws;
  uint16_t* tgt = (uint16_t*)(ws + WS_TGT_OFF);
  float4*   par = (float4*)(ws + WS_PAR_OFF);

  k_pre<<<(P_ * N_) / 256, 256, 0, stream>>>(kdesc, kscores, tgt, out);
  k_main<<<P_ * NB_ * CHUNKS_, 512, 0, stream>>>(dense, tgt, par);
  k_final<<<(P_ * N_) / 256, 256, 0, stream>>>(par, out);
}